// Round 11
// baseline (243.539 us; speedup 1.0000x reference)
//
#include <hip/hip_runtime.h>
#include <hip/hip_bf16.h>

// Fixed-capacity buckets: bucket(d) = d >> 8; bucket b's edge region is
// [b*cap, b*cap + count[b]). No global compaction needed — the gathers only
// consume per-node meta. cap = mean + ~10 sigma; overflow edges are dropped
// defensively (never triggers for this input).

#define MAXBUCK 512   // supports N <= 131072
#define CURSTRIDE 16  // pad cursors to 64B lines: kills same-line atomic contention

typedef unsigned int uint32;

__device__ __forceinline__ void fma4(float4& a, float s, const float4& w) {
    a.x = fmaf(s, w.x, a.x); a.y = fmaf(s, w.y, a.y);
    a.z = fmaf(s, w.z, a.z); a.w = fmaf(s, w.w, a.w);
}
// round-to-nearest-even fp32 -> bf16 (16-bit result)
__device__ __forceinline__ uint32 bf16rn(float f) {
    uint32 u = __float_as_uint(f);
    return (u + 0x7fffu + ((u >> 16) & 1u)) >> 16;
}
__device__ __forceinline__ float bflo(uint32 v) { return __uint_as_float(v << 16); }
__device__ __forceinline__ float bfhi(uint32 v) { return __uint_as_float(v & 0xffff0000u); }

// ---------------- bin edges into fixed bucket regions (packed uint32) ----------------
__global__ __launch_bounds__(1024) void k_bin(const int* __restrict__ src,
                                              const int* __restrict__ dst, int E,
                                              int nbuck, int cap,
                                              int* __restrict__ cursor,
                                              uint32* __restrict__ pairs) {
    __shared__ int hist[MAXBUCK];
    __shared__ int base_l[MAXBUCK];
    __shared__ int cur[MAXBUCK];
    __shared__ int dloc[4096];  // 16 KB: dst tile
    int t = threadIdx.x;
    int e0 = blockIdx.x * 4096;
    for (int i = t; i < MAXBUCK; i += 1024) { hist[i] = 0; cur[i] = 0; }
    __syncthreads();
    for (int i = t; i < 4096; i += 1024) {
        int e = e0 + i;
        if (e < E) {
            int d = dst[e];
            dloc[i] = d;
            atomicAdd(&hist[d >> 8], 1);
        }
    }
    __syncthreads();
    for (int i = t; i < nbuck; i += 1024)
        base_l[i] = hist[i] ? (i * cap + atomicAdd(&cursor[i * CURSTRIDE], hist[i])) : 0;
    __syncthreads();
    for (int i = t; i < 4096; i += 1024) {
        int e = e0 + i;
        if (e < E) {
            int d = dloc[i];
            int b = d >> 8;
            int p = atomicAdd(&cur[b], 1);
            int idx = base_l[b] + p;
            if (idx < (b + 1) * cap)  // overflow guard (never fires for this input)
                pairs[idx] = (uint32)src[e] | ((uint32)(d & 255) << 24);
        }
    }
}

// ---------------- per-bucket CSR fill + packed meta + dinv ----------------
// meta[node] = {rowstart, cnt, dinv_bits, 0} — one broadcast load per node (R10 win).
__global__ __launch_bounds__(1024) void k_fill2(const uint32* __restrict__ pairs,
                                                const int* __restrict__ bucket_cnt,
                                                int cap, int N,
                                                int* __restrict__ srclist,
                                                int4* __restrict__ meta,
                                                float* __restrict__ dinv) {
    __shared__ int hist[256];
    __shared__ int sh[256];
    __shared__ int rs_ex[256];
    __shared__ int cur[256];
    int b = blockIdx.x;
    int t = threadIdx.x;
    int start = b * cap;
    int end = start + min(bucket_cnt[b * CURSTRIDE], cap);
    int node0 = b << 8;

    if (t < 256) { hist[t] = 0; cur[t] = 0; }
    __syncthreads();
    for (int e = start + t; e < end; e += 1024)
        atomicAdd(&hist[pairs[e] >> 24], 1);
    __syncthreads();
    int v = 0;
    if (t < 256) { v = hist[t]; sh[t] = v; }
    __syncthreads();
    for (int off = 1; off < 256; off <<= 1) {
        int tmp = 0;
        if (t < 256 && t >= off) tmp = sh[t - off];
        __syncthreads();
        if (t < 256) sh[t] += tmp;
        __syncthreads();
    }
    if (t < 256) {
        rs_ex[t] = sh[t] - v;
        int node = node0 + t;
        if (node < N) {
            float dv = rsqrtf((float)(v + 1));
            meta[node] = make_int4(start + rs_ex[t], v, __float_as_int(dv), 0);
            dinv[node] = dv;   // original-order copy for k_gemm1
        }
    }
    __syncthreads();
    for (int e = start + t; e < end; e += 1024) {
        uint32 pr = pairs[e];
        int dl = pr >> 24;
        int p = atomicAdd(&cur[dl], 1);
        srclist[start + rs_ex[dl] + p] = (int)(pr & 0x00FFFFFFu);
    }
}

// ---------------- layer 1 GEMM: h1b = bf16((x @ W1) * dinv) ----------------
__global__ __launch_bounds__(256) void k_gemm1(const float* __restrict__ x,
                                               const float* __restrict__ W1,
                                               const float* __restrict__ dinv,
                                               uint32* __restrict__ h1b, int n) {
    __shared__ float W1s[64 * 64];    // 16 KB
    __shared__ float xs[32][68];      // 8.7 KB
    int t = threadIdx.x;
    int node0 = blockIdx.x * 32;
    int tx = t & 15;
    int ty = t >> 4;
    int na = ty * 2, nb = na + 1;
    float4 acc0 = make_float4(0.f, 0.f, 0.f, 0.f);
    float4 acc1 = make_float4(0.f, 0.f, 0.f, 0.f);
    const float4* W1v = (const float4*)W1;
    const float4* xv = (const float4*)x;
    float4* W1sv = (float4*)W1s;
    const float4* W1sq = (const float4*)W1s;

#pragma unroll 1
    for (int ph = 0; ph < 2; ph++) {
        __syncthreads();
        for (int i = t; i < 1024; i += 256) W1sv[i] = W1v[ph * 1024 + i];
        for (int i = t; i < 512; i += 256) {
            int nl = i >> 4, kq4 = i & 15;
            int node = node0 + nl;
            float4 v = make_float4(0.f, 0.f, 0.f, 0.f);
            if (node < n) v = xv[(size_t)node * 32 + ph * 16 + kq4];
            *(float4*)&xs[nl][kq4 * 4] = v;
        }
        __syncthreads();
#pragma unroll 4
        for (int kq = 0; kq < 16; kq++) {
            float4 xa = *(const float4*)&xs[na][kq * 4];
            float4 xb = *(const float4*)&xs[nb][kq * 4];
            float4 w0 = W1sq[(kq * 4 + 0) * 16 + tx];
            float4 w1 = W1sq[(kq * 4 + 1) * 16 + tx];
            float4 w2 = W1sq[(kq * 4 + 2) * 16 + tx];
            float4 w3 = W1sq[(kq * 4 + 3) * 16 + tx];
            fma4(acc0, xa.x, w0); fma4(acc0, xa.y, w1);
            fma4(acc0, xa.z, w2); fma4(acc0, xa.w, w3);
            fma4(acc1, xb.x, w0); fma4(acc1, xb.y, w1);
            fma4(acc1, xb.z, w2); fma4(acc1, xb.w, w3);
        }
    }
    int nA = node0 + na, nB = node0 + nb;
    if (nA < n) {
        float di = dinv[nA];
        uint2 pk = make_uint2(bf16rn(acc0.x * di) | (bf16rn(acc0.y * di) << 16),
                              bf16rn(acc0.z * di) | (bf16rn(acc0.w * di) << 16));
        ((uint2*)h1b)[(size_t)nA * 16 + tx] = pk;  // row = 32 uints = 16 uint2
    }
    if (nB < n) {
        float di = dinv[nB];
        uint2 pk = make_uint2(bf16rn(acc1.x * di) | (bf16rn(acc1.y * di) << 16),
                              bf16rn(acc1.z * di) | (bf16rn(acc1.w * di) << 16));
        ((uint2*)h1b)[(size_t)nB * 16 + tx] = pk;
    }
}

// ---- l1 gather helpers: drain/tail/extra are VERBATIM pair-version bodies ----
__device__ __forceinline__ void drain_l1(int sidx, int jj, int m0,
                                         const uint2* __restrict__ h1v, int j, int q,
                                         float& a0, float& a1, float& a2, float& a3) {
    for (; jj + 8 <= m0; jj += 8) {
        int s0 = __shfl(sidx, jj + q), s1 = __shfl(sidx, jj + 4 + q);
        uint2 v0 = h1v[(size_t)s0 * 16 + j], v1 = h1v[(size_t)s1 * 16 + j];
        a0 += bflo(v0.x) + bflo(v1.x);
        a1 += bfhi(v0.x) + bfhi(v1.x);
        a2 += bflo(v0.y) + bflo(v1.y);
        a3 += bfhi(v0.y) + bfhi(v1.y);
    }
    for (; jj < m0; jj += 4) {  // tail: clamp shfl lane, predicate the use
        int jidx = jj + q;
        int s = __shfl(sidx, min(jidx, m0 - 1));
        uint2 v = h1v[(size_t)s * 16 + j];
        if (jidx < m0) {
            a0 += bflo(v.x); a1 += bfhi(v.x);
            a2 += bflo(v.y); a3 += bfhi(v.y);
        }
    }
}
__device__ __forceinline__ void extra_l1(const int* __restrict__ srclist, int row, int m_all,
                                         int lane, const uint2* __restrict__ h1v, int j, int q,
                                         float& a0, float& a1, float& a2, float& a3) {
    for (int j0 = 64; j0 < m_all; j0 += 64) {  // degree > 64: ~never, kept for safety
        int m = min(64, m_all - j0);
        int sb = (lane < m) ? srclist[row + j0 + lane] : 0;
        int jj = 0;
        for (; jj + 8 <= m; jj += 8) {
            int s0 = __shfl(sb, jj + q), s1 = __shfl(sb, jj + 4 + q);
            uint2 v0 = h1v[(size_t)s0 * 16 + j], v1 = h1v[(size_t)s1 * 16 + j];
            a0 += bflo(v0.x) + bflo(v1.x);
            a1 += bfhi(v0.x) + bfhi(v1.x);
            a2 += bflo(v0.y) + bflo(v1.y);
            a3 += bfhi(v0.y) + bfhi(v1.y);
        }
        for (; jj < m; jj += 4) {
            int jidx = jj + q;
            int s = __shfl(sb, min(jidx, m - 1));
            uint2 v = h1v[(size_t)s * 16 + j];
            if (jidx < m) {
                a0 += bflo(v.x); a1 += bfhi(v.x);
                a2 += bflo(v.y); a3 += bfhi(v.y);
            }
        }
    }
}

// ------- L1 gather + finalize + GEMM2 — FOUR degree-independent nodes/wave -----
// R11: merged-8 over 4 nodes = 8 row-loads in flight with P~0.85 (all deg>=8
// per step) vs pair merged-16's 8-in-flight at P~0.32; meta/sidx stall levels
// shared 4 ways. merged-16 level dropped to keep register temps low (R5/R8
// lessons: VGPR>64 or extra shfl-tree kills it). Bodies verbatim from pair.
// QUARTER-wave (16 lanes x uint2 = 128B) reads one neighbor row.
__global__ __launch_bounds__(256) void k_gather_l1(const int4* __restrict__ meta,
                                                   const int* __restrict__ srclist,
                                                   const uint32* __restrict__ h1b,
                                                   const float* __restrict__ b1,
                                                   const float* __restrict__ W2,
                                                   unsigned short* __restrict__ h2b, int n) {
    __shared__ __align__(16) float W2s[64 * 32];  // 8 KB, W2s[k*32+c] (conflict-free)
    __shared__ __align__(16) float hb[16][64];    // 4 KB, one row per node
    int t = threadIdx.x;
    {   // stage W2 via float4: 512 float4s, 2 per thread
        const float4* W2v = (const float4*)W2;
        float4* W2sv = (float4*)W2s;
        W2sv[t] = W2v[t];
        W2sv[t + 256] = W2v[t + 256];
    }
    int wid = t >> 6, lane = t & 63;
    int nA = blockIdx.x * 16 + wid * 4;
    int nB = nA + 1, nC = nA + 2, nD = nA + 3;
    bool vA = (nA < n), vB = (nB < n), vC = (nC < n), vD = (nD < n);
    int j = lane & 15, q = lane >> 4;
    float4 bq = ((const float4*)b1)[j];  // hoisted

    // meta A..D co-issued: ONE 16B broadcast load per node
    int rowA = 0, mA = 0, rowB = 0, mB = 0, rowC = 0, mC = 0, rowD = 0, mD = 0;
    float diA = 0.f, diB = 0.f, diC = 0.f, diD = 0.f;
    uint2 svA = make_uint2(0u, 0u), svB = svA, svC = svA, svD = svA;
    const uint2* h1v = (const uint2*)h1b;
    if (vA) { int4 mv = meta[nA]; rowA = mv.x; mA = mv.y; diA = __int_as_float(mv.z);
              svA = h1v[(size_t)nA * 16 + j]; }
    if (vB) { int4 mv = meta[nB]; rowB = mv.x; mB = mv.y; diB = __int_as_float(mv.z);
              svB = h1v[(size_t)nB * 16 + j]; }
    if (vC) { int4 mv = meta[nC]; rowC = mv.x; mC = mv.y; diC = __int_as_float(mv.z);
              svC = h1v[(size_t)nC * 16 + j]; }
    if (vD) { int4 mv = meta[nD]; rowD = mv.x; mD = mv.y; diD = __int_as_float(mv.z);
              svD = h1v[(size_t)nD * 16 + j]; }
    int cA = min(64, mA), cB = min(64, mB), cC = min(64, mC), cD = min(64, mD);
    // srclist A..D co-issued
    int sxA = (lane < cA) ? srclist[rowA + lane] : 0;
    int sxB = (lane < cB) ? srclist[rowB + lane] : 0;
    int sxC = (lane < cC) ? srclist[rowC + lane] : 0;
    int sxD = (lane < cD) ? srclist[rowD + lane] : 0;

    float aA0 = 0.f, aA1 = 0.f, aA2 = 0.f, aA3 = 0.f;
    float aB0 = 0.f, aB1 = 0.f, aB2 = 0.f, aB3 = 0.f;
    float aC0 = 0.f, aC1 = 0.f, aC2 = 0.f, aC3 = 0.f;
    float aD0 = 0.f, aD1 = 0.f, aD2 = 0.f, aD3 = 0.f;
    int jA = 0, jB = 0, jC = 0, jD = 0;
    // merged-8 x 4 nodes: 8 row loads in flight, 32 rows/iter
    for (; jA + 8 <= cA && jB + 8 <= cB && jC + 8 <= cC && jD + 8 <= cD;
           jA += 8, jB += 8, jC += 8, jD += 8) {
        int sA0 = __shfl(sxA, jA + q), sA1 = __shfl(sxA, jA + 4 + q);
        int sB0 = __shfl(sxB, jB + q), sB1 = __shfl(sxB, jB + 4 + q);
        int sC0 = __shfl(sxC, jC + q), sC1 = __shfl(sxC, jC + 4 + q);
        int sD0 = __shfl(sxD, jD + q), sD1 = __shfl(sxD, jD + 4 + q);
        uint2 vA0 = h1v[(size_t)sA0 * 16 + j], vA1 = h1v[(size_t)sA1 * 16 + j];
        uint2 vB0 = h1v[(size_t)sB0 * 16 + j], vB1 = h1v[(size_t)sB1 * 16 + j];
        uint2 vC0 = h1v[(size_t)sC0 * 16 + j], vC1 = h1v[(size_t)sC1 * 16 + j];
        uint2 vD0 = h1v[(size_t)sD0 * 16 + j], vD1 = h1v[(size_t)sD1 * 16 + j];
        aA0 += bflo(vA0.x) + bflo(vA1.x); aA1 += bfhi(vA0.x) + bfhi(vA1.x);
        aA2 += bflo(vA0.y) + bflo(vA1.y); aA3 += bfhi(vA0.y) + bfhi(vA1.y);
        aB0 += bflo(vB0.x) + bflo(vB1.x); aB1 += bfhi(vB0.x) + bfhi(vB1.x);
        aB2 += bflo(vB0.y) + bflo(vB1.y); aB3 += bfhi(vB0.y) + bfhi(vB1.y);
        aC0 += bflo(vC0.x) + bflo(vC1.x); aC1 += bfhi(vC0.x) + bfhi(vC1.x);
        aC2 += bflo(vC0.y) + bflo(vC1.y); aC3 += bfhi(vC0.y) + bfhi(vC1.y);
        aD0 += bflo(vD0.x) + bflo(vD1.x); aD1 += bfhi(vD0.x) + bfhi(vD1.x);
        aD2 += bflo(vD0.y) + bflo(vD1.y); aD3 += bfhi(vD0.y) + bfhi(vD1.y);
    }
    // per-node drains + tails (pair-version bodies)
    drain_l1(sxA, jA, cA, h1v, j, q, aA0, aA1, aA2, aA3);
    drain_l1(sxB, jB, cB, h1v, j, q, aB0, aB1, aB2, aB3);
    drain_l1(sxC, jC, cC, h1v, j, q, aC0, aC1, aC2, aC3);
    drain_l1(sxD, jD, cD, h1v, j, q, aD0, aD1, aD2, aD3);
    // extra batches (degree > 64)
    extra_l1(srclist, rowA, mA, lane, h1v, j, q, aA0, aA1, aA2, aA3);
    extra_l1(srclist, rowB, mB, lane, h1v, j, q, aB0, aB1, aB2, aB3);
    extra_l1(srclist, rowC, mC, lane, h1v, j, q, aC0, aC1, aC2, aC3);
    extra_l1(srclist, rowD, mD, lane, h1v, j, q, aD0, aD1, aD2, aD3);

    // reduce + finalize
    aA0 += __shfl_xor(aA0, 16); aA0 += __shfl_xor(aA0, 32);
    aA1 += __shfl_xor(aA1, 16); aA1 += __shfl_xor(aA1, 32);
    aA2 += __shfl_xor(aA2, 16); aA2 += __shfl_xor(aA2, 32);
    aA3 += __shfl_xor(aA3, 16); aA3 += __shfl_xor(aA3, 32);
    aB0 += __shfl_xor(aB0, 16); aB0 += __shfl_xor(aB0, 32);
    aB1 += __shfl_xor(aB1, 16); aB1 += __shfl_xor(aB1, 32);
    aB2 += __shfl_xor(aB2, 16); aB2 += __shfl_xor(aB2, 32);
    aB3 += __shfl_xor(aB3, 16); aB3 += __shfl_xor(aB3, 32);
    aC0 += __shfl_xor(aC0, 16); aC0 += __shfl_xor(aC0, 32);
    aC1 += __shfl_xor(aC1, 16); aC1 += __shfl_xor(aC1, 32);
    aC2 += __shfl_xor(aC2, 16); aC2 += __shfl_xor(aC2, 32);
    aC3 += __shfl_xor(aC3, 16); aC3 += __shfl_xor(aC3, 32);
    aD0 += __shfl_xor(aD0, 16); aD0 += __shfl_xor(aD0, 32);
    aD1 += __shfl_xor(aD1, 16); aD1 += __shfl_xor(aD1, 32);
    aD2 += __shfl_xor(aD2, 16); aD2 += __shfl_xor(aD2, 32);
    aD3 += __shfl_xor(aD3, 16); aD3 += __shfl_xor(aD3, 32);
    if (vA && q == 0) {
        float4 hv;
        hv.x = fmaxf((aA0 + bflo(svA.x)) * diA + bq.x, 0.0f);
        hv.y = fmaxf((aA1 + bfhi(svA.x)) * diA + bq.y, 0.0f);
        hv.z = fmaxf((aA2 + bflo(svA.y)) * diA + bq.z, 0.0f);
        hv.w = fmaxf((aA3 + bfhi(svA.y)) * diA + bq.w, 0.0f);
        *(float4*)&hb[wid * 4 + 0][4 * j] = hv;
    }
    if (vB && q == 0) {
        float4 hv;
        hv.x = fmaxf((aB0 + bflo(svB.x)) * diB + bq.x, 0.0f);
        hv.y = fmaxf((aB1 + bfhi(svB.x)) * diB + bq.y, 0.0f);
        hv.z = fmaxf((aB2 + bflo(svB.y)) * diB + bq.z, 0.0f);
        hv.w = fmaxf((aB3 + bfhi(svB.y)) * diB + bq.w, 0.0f);
        *(float4*)&hb[wid * 4 + 1][4 * j] = hv;
    }
    if (vC && q == 0) {
        float4 hv;
        hv.x = fmaxf((aC0 + bflo(svC.x)) * diC + bq.x, 0.0f);
        hv.y = fmaxf((aC1 + bfhi(svC.x)) * diC + bq.y, 0.0f);
        hv.z = fmaxf((aC2 + bflo(svC.y)) * diC + bq.z, 0.0f);
        hv.w = fmaxf((aC3 + bfhi(svC.y)) * diC + bq.w, 0.0f);
        *(float4*)&hb[wid * 4 + 2][4 * j] = hv;
    }
    if (vD && q == 0) {
        float4 hv;
        hv.x = fmaxf((aD0 + bflo(svD.x)) * diD + bq.x, 0.0f);
        hv.y = fmaxf((aD1 + bfhi(svD.x)) * diD + bq.y, 0.0f);
        hv.z = fmaxf((aD2 + bflo(svD.y)) * diD + bq.z, 0.0f);
        hv.w = fmaxf((aD3 + bfhi(svD.y)) * diD + bq.w, 0.0f);
        *(float4*)&hb[wid * 4 + 3][4 * j] = hv;
    }
    __syncthreads();  // covers W2s staging and hb writes
    // GEMM2 split-k: half h sums k = h*32..h*32+31 for output col c (x4 nodes)
    int c = lane & 31, half = lane >> 5;
    int k0 = half * 32;
#pragma unroll
    for (int nd = 0; nd < 4; nd++) {
        int node = nA + nd;
        if (node >= n) break;
        float di = (nd == 0) ? diA : (nd == 1) ? diB : (nd == 2) ? diC : diD;
        float s = 0.0f;
        const float4* hb4 = (const float4*)&hb[wid * 4 + nd][k0];
#pragma unroll
        for (int kk = 0; kk < 8; kk++) {
            float4 h4 = hb4[kk];              // ds_read_b128, wave-uniform addr
            int kb = k0 + kk * 4;
            s = fmaf(h4.x, W2s[(kb + 0) * 32 + c], s);
            s = fmaf(h4.y, W2s[(kb + 1) * 32 + c], s);
            s = fmaf(h4.z, W2s[(kb + 2) * 32 + c], s);
            s = fmaf(h4.w, W2s[(kb + 3) * 32 + c], s);
        }
        s += __shfl_xor(s, 32);
        if (half == 0) h2b[(size_t)node * 32 + c] = (unsigned short)bf16rn(s * di);
    }
}

// ---- l2 gather helpers: drain/tail/extra verbatim from pair version ----
__device__ __forceinline__ void drain_l2(int sidx, int jj, int m0,
                                         const uint2* __restrict__ h2v, int j, int o,
                                         float& a0, float& a1, float& a2, float& a3) {
    for (; jj + 8 <= m0; jj += 8) {
        int s0 = __shfl(sidx, jj + o);
        uint2 v0 = h2v[(size_t)s0 * 8 + j];
        a0 += bflo(v0.x); a1 += bfhi(v0.x);
        a2 += bflo(v0.y); a3 += bfhi(v0.y);
    }
    if (jj < m0) {  // tail: clamp shfl lane, predicate the use
        int jidx = jj + o;
        int s = __shfl(sidx, min(jidx, m0 - 1));
        uint2 v = h2v[(size_t)s * 8 + j];
        if (jidx < m0) {
            a0 += bflo(v.x); a1 += bfhi(v.x);
            a2 += bflo(v.y); a3 += bfhi(v.y);
        }
    }
}
__device__ __forceinline__ void extra_l2(const int* __restrict__ srclist, int row, int m_all,
                                         int lane, const uint2* __restrict__ h2v, int j, int o,
                                         float& a0, float& a1, float& a2, float& a3) {
    for (int j0 = 64; j0 < m_all; j0 += 64) {  // degree > 64: ~never, kept for safety
        int m = min(64, m_all - j0);
        int sb = (lane < m) ? srclist[row + j0 + lane] : 0;
        int jj = 0;
        for (; jj + 8 <= m; jj += 8) {
            int s0 = __shfl(sb, jj + o);
            uint2 v0 = h2v[(size_t)s0 * 8 + j];
            a0 += bflo(v0.x); a1 += bfhi(v0.x);
            a2 += bflo(v0.y); a3 += bfhi(v0.y);
        }
        if (jj < m) {
            int jidx = jj + o;
            int s = __shfl(sb, min(jidx, m - 1));
            uint2 v = h2v[(size_t)s * 8 + j];
            if (jidx < m) {
                a0 += bflo(v.x); a1 += bfhi(v.x);
                a2 += bflo(v.y); a3 += bfhi(v.y);
            }
        }
    }
}

// ------- L2 gather + finalize — FOUR degree-independent nodes per wave ---------
// EIGHTH-wave (8 lanes x uint2 = 64B) reads one row; merged-8 x4 = 4 loads in
// flight with P~0.85 + 4-way meta/sidx stall sharing.
__global__ __launch_bounds__(256) void k_gather_l2(const int4* __restrict__ meta,
                                                   const int* __restrict__ srclist,
                                                   const uint32* __restrict__ h2b,
                                                   const float* __restrict__ b2v,
                                                   float* __restrict__ out, int n) {
    int t = threadIdx.x;
    int wid = t >> 6, lane = t & 63;
    int nA = blockIdx.x * 16 + wid * 4;
    if (nA >= n) return;  // whole wave exits together (no syncthreads below)
    int nB = nA + 1, nC = nA + 2, nD = nA + 3;
    bool vB_ = (nB < n), vC_ = (nC < n), vD_ = (nD < n);
    int j = lane & 7, o = lane >> 3;
    float4 bq = ((const float4*)b2v)[j];  // hoisted

    const uint2* h2v = (const uint2*)h2b;
    int4 mvA = meta[nA];
    int rowA = mvA.x, mA = mvA.y;
    float diA = __int_as_float(mvA.z);
    uint2 svA = h2v[(size_t)nA * 8 + j];
    int rowB = 0, mB = 0, rowC = 0, mC = 0, rowD = 0, mD = 0;
    float diB = 0.f, diC = 0.f, diD = 0.f;
    uint2 svB = make_uint2(0u, 0u), svC = svB, svD = svB;
    if (vB_) { int4 mv = meta[nB]; rowB = mv.x; mB = mv.y; diB = __int_as_float(mv.z);
               svB = h2v[(size_t)nB * 8 + j]; }
    if (vC_) { int4 mv = meta[nC]; rowC = mv.x; mC = mv.y; diC = __int_as_float(mv.z);
               svC = h2v[(size_t)nC * 8 + j]; }
    if (vD_) { int4 mv = meta[nD]; rowD = mv.x; mD = mv.y; diD = __int_as_float(mv.z);
               svD = h2v[(size_t)nD * 8 + j]; }
    int cA = min(64, mA), cB = min(64, mB), cC = min(64, mC), cD = min(64, mD);
    int sxA = (lane < cA) ? srclist[rowA + lane] : 0;
    int sxB = (lane < cB) ? srclist[rowB + lane] : 0;
    int sxC = (lane < cC) ? srclist[rowC + lane] : 0;
    int sxD = (lane < cD) ? srclist[rowD + lane] : 0;

    float aA0 = 0.f, aA1 = 0.f, aA2 = 0.f, aA3 = 0.f;
    float aB0 = 0.f, aB1 = 0.f, aB2 = 0.f, aB3 = 0.f;
    float aC0 = 0.f, aC1 = 0.f, aC2 = 0.f, aC3 = 0.f;
    float aD0 = 0.f, aD1 = 0.f, aD2 = 0.f, aD3 = 0.f;
    int jA = 0, jB = 0, jC = 0, jD = 0;
    // merged-8 x 4 nodes: 4 row loads in flight, 32 rows/iter
    for (; jA + 8 <= cA && jB + 8 <= cB && jC + 8 <= cC && jD + 8 <= cD;
           jA += 8, jB += 8, jC += 8, jD += 8) {
        int sA0 = __shfl(sxA, jA + o);
        int sB0 = __shfl(sxB, jB + o);
        int sC0 = __shfl(sxC, jC + o);
        int sD0 = __shfl(sxD, jD + o);
        uint2 vA0 = h2v[(size_t)sA0 * 8 + j];
        uint2 vB0 = h2v[(size_t)sB0 * 8 + j];
        uint2 vC0 = h2v[(size_t)sC0 * 8 + j];
        uint2 vD0 = h2v[(size_t)sD0 * 8 + j];
        aA0 += bflo(vA0.x); aA1 += bfhi(vA0.x);
        aA2 += bflo(vA0.y); aA3 += bfhi(vA0.y);
        aB0 += bflo(vB0.x); aB1 += bfhi(vB0.x);
        aB2 += bflo(vB0.y); aB3 += bfhi(vB0.y);
        aC0 += bflo(vC0.x); aC1 += bfhi(vC0.x);
        aC2 += bflo(vC0.y); aC3 += bfhi(vC0.y);
        aD0 += bflo(vD0.x); aD1 += bfhi(vD0.x);
        aD2 += bflo(vD0.y); aD3 += bfhi(vD0.y);
    }
    drain_l2(sxA, jA, cA, h2v, j, o, aA0, aA1, aA2, aA3);
    drain_l2(sxB, jB, cB, h2v, j, o, aB0, aB1, aB2, aB3);
    drain_l2(sxC, jC, cC, h2v, j, o, aC0, aC1, aC2, aC3);
    drain_l2(sxD, jD, cD, h2v, j, o, aD0, aD1, aD2, aD3);
    extra_l2(srclist, rowA, mA, lane, h2v, j, o, aA0, aA1, aA2, aA3);
    extra_l2(srclist, rowB, mB, lane, h2v, j, o, aB0, aB1, aB2, aB3);
    extra_l2(srclist, rowC, mC, lane, h2v, j, o, aC0, aC1, aC2, aC3);
    extra_l2(srclist, rowD, mD, lane, h2v, j, o, aD0, aD1, aD2, aD3);

    aA0 += __shfl_xor(aA0, 8); aA0 += __shfl_xor(aA0, 16); aA0 += __shfl_xor(aA0, 32);
    aA1 += __shfl_xor(aA1, 8); aA1 += __shfl_xor(aA1, 16); aA1 += __shfl_xor(aA1, 32);
    aA2 += __shfl_xor(aA2, 8); aA2 += __shfl_xor(aA2, 16); aA2 += __shfl_xor(aA2, 32);
    aA3 += __shfl_xor(aA3, 8); aA3 += __shfl_xor(aA3, 16); aA3 += __shfl_xor(aA3, 32);
    aB0 += __shfl_xor(aB0, 8); aB0 += __shfl_xor(aB0, 16); aB0 += __shfl_xor(aB0, 32);
    aB1 += __shfl_xor(aB1, 8); aB1 += __shfl_xor(aB1, 16); aB1 += __shfl_xor(aB1, 32);
    aB2 += __shfl_xor(aB2, 8); aB2 += __shfl_xor(aB2, 16); aB2 += __shfl_xor(aB2, 32);
    aB3 += __shfl_xor(aB3, 8); aB3 += __shfl_xor(aB3, 16); aB3 += __shfl_xor(aB3, 32);
    aC0 += __shfl_xor(aC0, 8); aC0 += __shfl_xor(aC0, 16); aC0 += __shfl_xor(aC0, 32);
    aC1 += __shfl_xor(aC1, 8); aC1 += __shfl_xor(aC1, 16); aC1 += __shfl_xor(aC1, 32);
    aC2 += __shfl_xor(aC2, 8); aC2 += __shfl_xor(aC2, 16); aC2 += __shfl_xor(aC2, 32);
    aC3 += __shfl_xor(aC3, 8); aC3 += __shfl_xor(aC3, 16); aC3 += __shfl_xor(aC3, 32);
    aD0 += __shfl_xor(aD0, 8); aD0 += __shfl_xor(aD0, 16); aD0 += __shfl_xor(aD0, 32);
    aD1 += __shfl_xor(aD1, 8); aD1 += __shfl_xor(aD1, 16); aD1 += __shfl_xor(aD1, 32);
    aD2 += __shfl_xor(aD2, 8); aD2 += __shfl_xor(aD2, 16); aD2 += __shfl_xor(aD2, 32);
    aD3 += __shfl_xor(aD3, 8); aD3 += __shfl_xor(aD3, 16); aD3 += __shfl_xor(aD3, 32);
    if (o == 0) {
        float4 ov;
        ov.x = (aA0 + bflo(svA.x)) * diA + bq.x;
        ov.y = (aA1 + bfhi(svA.x)) * diA + bq.y;
        ov.z = (aA2 + bflo(svA.y)) * diA + bq.z;
        ov.w = (aA3 + bfhi(svA.y)) * diA + bq.w;
        ((float4*)out)[(size_t)nA * 8 + j] = ov;
        if (vB_) {
            float4 ob;
            ob.x = (aB0 + bflo(svB.x)) * diB + bq.x;
            ob.y = (aB1 + bfhi(svB.x)) * diB + bq.y;
            ob.z = (aB2 + bflo(svB.y)) * diB + bq.z;
            ob.w = (aB3 + bfhi(svB.y)) * diB + bq.w;
            ((float4*)out)[(size_t)nB * 8 + j] = ob;
        }
        if (vC_) {
            float4 oc;
            oc.x = (aC0 + bflo(svC.x)) * diC + bq.x;
            oc.y = (aC1 + bfhi(svC.x)) * diC + bq.y;
            oc.z = (aC2 + bflo(svC.y)) * diC + bq.z;
            oc.w = (aC3 + bfhi(svC.y)) * diC + bq.w;
            ((float4*)out)[(size_t)nC * 8 + j] = oc;
        }
        if (vD_) {
            float4 od;
            od.x = (aD0 + bflo(svD.x)) * diD + bq.x;
            od.y = (aD1 + bfhi(svD.x)) * diD + bq.y;
            od.z = (aD2 + bflo(svD.y)) * diD + bq.z;
            od.w = (aD3 + bfhi(svD.y)) * diD + bq.w;
            ((float4*)out)[(size_t)nD * 8 + j] = od;
        }
    }
}

extern "C" void kernel_launch(void* const* d_in, const int* in_sizes, int n_in,
                              void* d_out, int out_size, void* d_ws, size_t ws_size,
                              hipStream_t stream) {
    const float* x  = (const float*)d_in[0];
    const int*   ei = (const int*)d_in[1];
    const float* W1 = (const float*)d_in[2];
    const float* b1 = (const float*)d_in[3];
    const float* W2 = (const float*)d_in[4];
    const float* b2 = (const float*)d_in[5];
    float* out = (float*)d_out;

    const int N = in_sizes[0] / 128;  // 100000
    const int E = in_sizes[1] / 2;    // 1600000
    const int* src = ei;
    const int* dst = ei + E;
    const int nbuck = (N + 255) >> 8;  // 391

    // per-bucket capacity: mean + mean/8 + 256, rounded up to 64 (~mu+10sigma)
    int mean = (E + nbuck - 1) / nbuck;
    int cap = (mean + (mean >> 3) + 256 + 63) & ~63;     // 4864 for this input
    size_t region = (size_t)nbuck * cap;                 // ~1.9M entries, 7.6 MB

    char* p = (char*)d_ws;
    uint32* pairs      = (uint32*)p;    p += region * 4;          // 7.6 MB
    int* srclist       = (int*)p;       p += region * 4;          // 7.6 MB
    uint32* h1b        = (uint32*)p;    p += (size_t)N * 64 * 2;  // 12.8 MB
    uint32* h2b        = (uint32*)p;    p += (size_t)N * 32 * 2;  // 6.4 MB
    int* cursor        = (int*)p;       p += MAXBUCK * CURSTRIDE * 4;  // 32 KB
    int4* meta         = (int4*)p;      p += (size_t)N * 16;      // 1.6 MB packed meta
    float* dinv        = (float*)p;     p += (size_t)N * 4;       // total ~38 MB

    // zero-based per-bucket cursors (init via memset, no initcur launch)
    hipMemsetAsync(cursor, 0, (size_t)nbuck * CURSTRIDE * 4, stream);
    k_bin<<<(E + 4095) / 4096, 1024, 0, stream>>>(src, dst, E, nbuck, cap, cursor, pairs);
    k_fill2<<<nbuck, 1024, 0, stream>>>(pairs, cursor, cap, N, srclist, meta, dinv);

    k_gemm1<<<(N + 31) / 32, 256, 0, stream>>>(x, W1, dinv, h1b, N);
    k_gather_l1<<<(N + 15) / 16, 256, 0, stream>>>(meta, srclist, h1b,
                                                   b1, W2, (unsigned short*)h2b, N);
    k_gather_l2<<<(N + 15) / 16, 256, 0, stream>>>(meta, srclist, h2b, b2, out, N);
}

// Round 12
// 227.990 us; speedup vs baseline: 1.0682x; 1.0682x over previous
//
#include <hip/hip_runtime.h>
#include <hip/hip_bf16.h>

// Fixed-capacity buckets: bucket(d) = d >> 8; bucket b's edge region is
// [b*cap, b*cap + count[b]). No global compaction needed — the gathers only
// consume per-node meta. cap = mean + ~10 sigma; overflow edges are dropped
// defensively (never triggers for this input).
//
// R12 = R10 verbatim (verified optimum, 228.3us). Ledger: wins were uint2 row
// loads (R1), 2-node pair merge (R4), packed meta (R10), preprocessing tweaks
// (R2/R6). All six structural bets (persistent waves R3, per-iter idx loads R5,
// degree sort R7, uint4 R8, 1024-thr gather R9, 4-node merge R11) regressed.

#define MAXBUCK 512   // supports N <= 131072
#define CURSTRIDE 16  // pad cursors to 64B lines: kills same-line atomic contention

typedef unsigned int uint32;

__device__ __forceinline__ void fma4(float4& a, float s, const float4& w) {
    a.x = fmaf(s, w.x, a.x); a.y = fmaf(s, w.y, a.y);
    a.z = fmaf(s, w.z, a.z); a.w = fmaf(s, w.w, a.w);
}
// round-to-nearest-even fp32 -> bf16 (16-bit result)
__device__ __forceinline__ uint32 bf16rn(float f) {
    uint32 u = __float_as_uint(f);
    return (u + 0x7fffu + ((u >> 16) & 1u)) >> 16;
}
__device__ __forceinline__ float bflo(uint32 v) { return __uint_as_float(v << 16); }
__device__ __forceinline__ float bfhi(uint32 v) { return __uint_as_float(v & 0xffff0000u); }

// ---------------- bin edges into fixed bucket regions (packed uint32) ----------------
__global__ __launch_bounds__(1024) void k_bin(const int* __restrict__ src,
                                              const int* __restrict__ dst, int E,
                                              int nbuck, int cap,
                                              int* __restrict__ cursor,
                                              uint32* __restrict__ pairs) {
    __shared__ int hist[MAXBUCK];
    __shared__ int base_l[MAXBUCK];
    __shared__ int cur[MAXBUCK];
    __shared__ int dloc[4096];  // 16 KB: dst tile
    int t = threadIdx.x;
    int e0 = blockIdx.x * 4096;
    for (int i = t; i < MAXBUCK; i += 1024) { hist[i] = 0; cur[i] = 0; }
    __syncthreads();
    for (int i = t; i < 4096; i += 1024) {
        int e = e0 + i;
        if (e < E) {
            int d = dst[e];
            dloc[i] = d;
            atomicAdd(&hist[d >> 8], 1);
        }
    }
    __syncthreads();
    for (int i = t; i < nbuck; i += 1024)
        base_l[i] = hist[i] ? (i * cap + atomicAdd(&cursor[i * CURSTRIDE], hist[i])) : 0;
    __syncthreads();
    for (int i = t; i < 4096; i += 1024) {
        int e = e0 + i;
        if (e < E) {
            int d = dloc[i];
            int b = d >> 8;
            int p = atomicAdd(&cur[b], 1);
            int idx = base_l[b] + p;
            if (idx < (b + 1) * cap)  // overflow guard (never fires for this input)
                pairs[idx] = (uint32)src[e] | ((uint32)(d & 255) << 24);
        }
    }
}

// ---------------- per-bucket CSR fill + packed meta + dinv ----------------
// meta[node] = {rowstart, cnt, dinv_bits, 0} — one broadcast load per node.
__global__ __launch_bounds__(1024) void k_fill2(const uint32* __restrict__ pairs,
                                                const int* __restrict__ bucket_cnt,
                                                int cap, int N,
                                                int* __restrict__ srclist,
                                                int4* __restrict__ meta,
                                                float* __restrict__ dinv) {
    __shared__ int hist[256];
    __shared__ int sh[256];
    __shared__ int rs_ex[256];
    __shared__ int cur[256];
    int b = blockIdx.x;
    int t = threadIdx.x;
    int start = b * cap;
    int end = start + min(bucket_cnt[b * CURSTRIDE], cap);
    int node0 = b << 8;

    if (t < 256) { hist[t] = 0; cur[t] = 0; }
    __syncthreads();
    for (int e = start + t; e < end; e += 1024)
        atomicAdd(&hist[pairs[e] >> 24], 1);
    __syncthreads();
    int v = 0;
    if (t < 256) { v = hist[t]; sh[t] = v; }
    __syncthreads();
    for (int off = 1; off < 256; off <<= 1) {
        int tmp = 0;
        if (t < 256 && t >= off) tmp = sh[t - off];
        __syncthreads();
        if (t < 256) sh[t] += tmp;
        __syncthreads();
    }
    if (t < 256) {
        rs_ex[t] = sh[t] - v;
        int node = node0 + t;
        if (node < N) {
            float dv = rsqrtf((float)(v + 1));
            meta[node] = make_int4(start + rs_ex[t], v, __float_as_int(dv), 0);
            dinv[node] = dv;   // original-order copy for k_gemm1
        }
    }
    __syncthreads();
    for (int e = start + t; e < end; e += 1024) {
        uint32 pr = pairs[e];
        int dl = pr >> 24;
        int p = atomicAdd(&cur[dl], 1);
        srclist[start + rs_ex[dl] + p] = (int)(pr & 0x00FFFFFFu);
    }
}

// ---------------- layer 1 GEMM: h1b = bf16((x @ W1) * dinv) ----------------
// 32 nodes/block; thread = 2 nodes x 4 cols. k split in two phases
// (LDS 24.7 KB -> 6 blocks/CU). FMA order == original kq 0..31 (bit-identical).
__global__ __launch_bounds__(256) void k_gemm1(const float* __restrict__ x,
                                               const float* __restrict__ W1,
                                               const float* __restrict__ dinv,
                                               uint32* __restrict__ h1b, int n) {
    __shared__ float W1s[64 * 64];    // 16 KB
    __shared__ float xs[32][68];      // 8.7 KB
    int t = threadIdx.x;
    int node0 = blockIdx.x * 32;
    int tx = t & 15;
    int ty = t >> 4;
    int na = ty * 2, nb = na + 1;
    float4 acc0 = make_float4(0.f, 0.f, 0.f, 0.f);
    float4 acc1 = make_float4(0.f, 0.f, 0.f, 0.f);
    const float4* W1v = (const float4*)W1;
    const float4* xv = (const float4*)x;
    float4* W1sv = (float4*)W1s;
    const float4* W1sq = (const float4*)W1s;

#pragma unroll 1
    for (int ph = 0; ph < 2; ph++) {
        __syncthreads();
        for (int i = t; i < 1024; i += 256) W1sv[i] = W1v[ph * 1024 + i];
        for (int i = t; i < 512; i += 256) {
            int nl = i >> 4, kq4 = i & 15;
            int node = node0 + nl;
            float4 v = make_float4(0.f, 0.f, 0.f, 0.f);
            if (node < n) v = xv[(size_t)node * 32 + ph * 16 + kq4];
            *(float4*)&xs[nl][kq4 * 4] = v;
        }
        __syncthreads();
#pragma unroll 4
        for (int kq = 0; kq < 16; kq++) {
            float4 xa = *(const float4*)&xs[na][kq * 4];
            float4 xb = *(const float4*)&xs[nb][kq * 4];
            float4 w0 = W1sq[(kq * 4 + 0) * 16 + tx];
            float4 w1 = W1sq[(kq * 4 + 1) * 16 + tx];
            float4 w2 = W1sq[(kq * 4 + 2) * 16 + tx];
            float4 w3 = W1sq[(kq * 4 + 3) * 16 + tx];
            fma4(acc0, xa.x, w0); fma4(acc0, xa.y, w1);
            fma4(acc0, xa.z, w2); fma4(acc0, xa.w, w3);
            fma4(acc1, xb.x, w0); fma4(acc1, xb.y, w1);
            fma4(acc1, xb.z, w2); fma4(acc1, xb.w, w3);
        }
    }
    int nA = node0 + na, nB = node0 + nb;
    if (nA < n) {
        float di = dinv[nA];
        uint2 pk = make_uint2(bf16rn(acc0.x * di) | (bf16rn(acc0.y * di) << 16),
                              bf16rn(acc0.z * di) | (bf16rn(acc0.w * di) << 16));
        ((uint2*)h1b)[(size_t)nA * 16 + tx] = pk;  // row = 32 uints = 16 uint2
    }
    if (nB < n) {
        float di = dinv[nB];
        uint2 pk = make_uint2(bf16rn(acc1.x * di) | (bf16rn(acc1.y * di) << 16),
                              bf16rn(acc1.z * di) | (bf16rn(acc1.w * di) << 16));
        ((uint2*)h1b)[(size_t)nB * 16 + tx] = pk;
    }
}

// ------- L1 gather + finalize + GEMM2 — two nodes/wave + packed meta (optimum) -
// QUARTER-wave (16 lanes x uint2 = 128B) reads one neighbor row.
__global__ __launch_bounds__(256) void k_gather_l1(const int4* __restrict__ meta,
                                                   const int* __restrict__ srclist,
                                                   const uint32* __restrict__ h1b,
                                                   const float* __restrict__ b1,
                                                   const float* __restrict__ W2,
                                                   unsigned short* __restrict__ h2b, int n) {
    __shared__ __align__(16) float W2s[64 * 32];  // 8 KB, W2s[k*32+c] (conflict-free)
    __shared__ __align__(16) float hb[8][64];     // 2 KB, one row per node
    int t = threadIdx.x;
    {   // stage W2 via float4: 512 float4s, 2 per thread
        const float4* W2v = (const float4*)W2;
        float4* W2sv = (float4*)W2s;
        W2sv[t] = W2v[t];
        W2sv[t + 256] = W2v[t + 256];
    }
    int wid = t >> 6, lane = t & 63;
    int nodeA = blockIdx.x * 8 + wid * 2;
    int nodeB = nodeA + 1;
    bool validA = (nodeA < n), validB = (nodeB < n);
    int j = lane & 15, q = lane >> 4;
    float4 bq = ((const float4*)b1)[j];  // hoisted: co-issues with meta loads

    // meta A+B co-issued: ONE 16B broadcast load per node
    int rowA = 0, mA = 0, rowB = 0, mB = 0;
    float diA = 0.0f, diB = 0.0f;
    uint2 svA = make_uint2(0u, 0u), svB = make_uint2(0u, 0u);
    const uint2* h1v = (const uint2*)h1b;
    if (validA) {
        int4 mv = meta[nodeA];
        rowA = mv.x; mA = mv.y; diA = __int_as_float(mv.z);
        svA = h1v[(size_t)nodeA * 16 + j];
    }
    if (validB) {
        int4 mv = meta[nodeB];
        rowB = mv.x; mB = mv.y; diB = __int_as_float(mv.z);
        svB = h1v[(size_t)nodeB * 16 + j];
    }
    int mA0 = min(64, mA), mB0 = min(64, mB);  // first-batch sizes (wave-uniform)
    // srclist A+B co-issued
    int sidxA = (lane < mA0) ? srclist[rowA + lane] : 0;
    int sidxB = (lane < mB0) ? srclist[rowB + lane] : 0;

    float aA0 = 0.f, aA1 = 0.f, aA2 = 0.f, aA3 = 0.f;
    float aB0 = 0.f, aB1 = 0.f, aB2 = 0.f, aB3 = 0.f;
    int jjA = 0, jjB = 0;
    // merged-16: 16 rows of A + 16 rows of B, 8 row loads in flight
    for (; jjA + 16 <= mA0 && jjB + 16 <= mB0; jjA += 16, jjB += 16) {
        int sA0 = __shfl(sidxA, jjA + q),      sA1 = __shfl(sidxA, jjA + 4 + q);
        int sA2 = __shfl(sidxA, jjA + 8 + q),  sA3 = __shfl(sidxA, jjA + 12 + q);
        int sB0 = __shfl(sidxB, jjB + q),      sB1 = __shfl(sidxB, jjB + 4 + q);
        int sB2 = __shfl(sidxB, jjB + 8 + q),  sB3 = __shfl(sidxB, jjB + 12 + q);
        uint2 vA0 = h1v[(size_t)sA0 * 16 + j], vA1 = h1v[(size_t)sA1 * 16 + j];
        uint2 vA2 = h1v[(size_t)sA2 * 16 + j], vA3 = h1v[(size_t)sA3 * 16 + j];
        uint2 vB0 = h1v[(size_t)sB0 * 16 + j], vB1 = h1v[(size_t)sB1 * 16 + j];
        uint2 vB2 = h1v[(size_t)sB2 * 16 + j], vB3 = h1v[(size_t)sB3 * 16 + j];
        aA0 += (bflo(vA0.x) + bflo(vA1.x)) + (bflo(vA2.x) + bflo(vA3.x));
        aA1 += (bfhi(vA0.x) + bfhi(vA1.x)) + (bfhi(vA2.x) + bfhi(vA3.x));
        aA2 += (bflo(vA0.y) + bflo(vA1.y)) + (bflo(vA2.y) + bflo(vA3.y));
        aA3 += (bfhi(vA0.y) + bfhi(vA1.y)) + (bfhi(vA2.y) + bfhi(vA3.y));
        aB0 += (bflo(vB0.x) + bflo(vB1.x)) + (bflo(vB2.x) + bflo(vB3.x));
        aB1 += (bfhi(vB0.x) + bfhi(vB1.x)) + (bfhi(vB2.x) + bfhi(vB3.x));
        aB2 += (bflo(vB0.y) + bflo(vB1.y)) + (bflo(vB2.y) + bflo(vB3.y));
        aB3 += (bfhi(vB0.y) + bfhi(vB1.y)) + (bfhi(vB2.y) + bfhi(vB3.y));
    }
    // merged-8: 8 rows each, 4 row loads in flight
    for (; jjA + 8 <= mA0 && jjB + 8 <= mB0; jjA += 8, jjB += 8) {
        int sA0 = __shfl(sidxA, jjA + q), sA1 = __shfl(sidxA, jjA + 4 + q);
        int sB0 = __shfl(sidxB, jjB + q), sB1 = __shfl(sidxB, jjB + 4 + q);
        uint2 vA0 = h1v[(size_t)sA0 * 16 + j], vA1 = h1v[(size_t)sA1 * 16 + j];
        uint2 vB0 = h1v[(size_t)sB0 * 16 + j], vB1 = h1v[(size_t)sB1 * 16 + j];
        aA0 += bflo(vA0.x) + bflo(vA1.x);
        aA1 += bfhi(vA0.x) + bfhi(vA1.x);
        aA2 += bflo(vA0.y) + bflo(vA1.y);
        aA3 += bfhi(vA0.y) + bfhi(vA1.y);
        aB0 += bflo(vB0.x) + bflo(vB1.x);
        aB1 += bfhi(vB0.x) + bfhi(vB1.x);
        aB2 += bflo(vB0.y) + bflo(vB1.y);
        aB3 += bfhi(vB0.y) + bfhi(vB1.y);
    }
    // drain A (first batch)
    for (; jjA + 8 <= mA0; jjA += 8) {
        int s0 = __shfl(sidxA, jjA + q), s1 = __shfl(sidxA, jjA + 4 + q);
        uint2 v0 = h1v[(size_t)s0 * 16 + j], v1 = h1v[(size_t)s1 * 16 + j];
        aA0 += bflo(v0.x) + bflo(v1.x);
        aA1 += bfhi(v0.x) + bfhi(v1.x);
        aA2 += bflo(v0.y) + bflo(v1.y);
        aA3 += bfhi(v0.y) + bfhi(v1.y);
    }
    for (; jjA < mA0; jjA += 4) {  // tail: clamp shfl lane, predicate the use
        int jidx = jjA + q;
        int s = __shfl(sidxA, min(jidx, mA0 - 1));
        uint2 v = h1v[(size_t)s * 16 + j];
        if (jidx < mA0) {
            aA0 += bflo(v.x); aA1 += bfhi(v.x);
            aA2 += bflo(v.y); aA3 += bfhi(v.y);
        }
    }
    // drain B (first batch)
    for (; jjB + 8 <= mB0; jjB += 8) {
        int s0 = __shfl(sidxB, jjB + q), s1 = __shfl(sidxB, jjB + 4 + q);
        uint2 v0 = h1v[(size_t)s0 * 16 + j], v1 = h1v[(size_t)s1 * 16 + j];
        aB0 += bflo(v0.x) + bflo(v1.x);
        aB1 += bfhi(v0.x) + bfhi(v1.x);
        aB2 += bflo(v0.y) + bflo(v1.y);
        aB3 += bfhi(v0.y) + bfhi(v1.y);
    }
    for (; jjB < mB0; jjB += 4) {
        int jidx = jjB + q;
        int s = __shfl(sidxB, min(jidx, mB0 - 1));
        uint2 v = h1v[(size_t)s * 16 + j];
        if (jidx < mB0) {
            aB0 += bflo(v.x); aB1 += bfhi(v.x);
            aB2 += bflo(v.y); aB3 += bfhi(v.y);
        }
    }
    // extra batches (degree > 64; essentially never for this input, kept for safety)
    for (int j0 = 64; j0 < mA; j0 += 64) {
        int m = min(64, mA - j0);
        int sb = (lane < m) ? srclist[rowA + j0 + lane] : 0;
        int jj = 0;
        for (; jj + 8 <= m; jj += 8) {
            int s0 = __shfl(sb, jj + q), s1 = __shfl(sb, jj + 4 + q);
            uint2 v0 = h1v[(size_t)s0 * 16 + j], v1 = h1v[(size_t)s1 * 16 + j];
            aA0 += bflo(v0.x) + bflo(v1.x);
            aA1 += bfhi(v0.x) + bfhi(v1.x);
            aA2 += bflo(v0.y) + bflo(v1.y);
            aA3 += bfhi(v0.y) + bfhi(v1.y);
        }
        for (; jj < m; jj += 4) {
            int jidx = jj + q;
            int s = __shfl(sb, min(jidx, m - 1));
            uint2 v = h1v[(size_t)s * 16 + j];
            if (jidx < m) {
                aA0 += bflo(v.x); aA1 += bfhi(v.x);
                aA2 += bflo(v.y); aA3 += bfhi(v.y);
            }
        }
    }
    for (int j0 = 64; j0 < mB; j0 += 64) {
        int m = min(64, mB - j0);
        int sb = (lane < m) ? srclist[rowB + j0 + lane] : 0;
        int jj = 0;
        for (; jj + 8 <= m; jj += 8) {
            int s0 = __shfl(sb, jj + q), s1 = __shfl(sb, jj + 4 + q);
            uint2 v0 = h1v[(size_t)s0 * 16 + j], v1 = h1v[(size_t)s1 * 16 + j];
            aB0 += bflo(v0.x) + bflo(v1.x);
            aB1 += bfhi(v0.x) + bfhi(v1.x);
            aB2 += bflo(v0.y) + bflo(v1.y);
            aB3 += bfhi(v0.y) + bfhi(v1.y);
        }
        for (; jj < m; jj += 4) {
            int jidx = jj + q;
            int s = __shfl(sb, min(jidx, m - 1));
            uint2 v = h1v[(size_t)s * 16 + j];
            if (jidx < m) {
                aB0 += bflo(v.x); aB1 += bfhi(v.x);
                aB2 += bflo(v.y); aB3 += bfhi(v.y);
            }
        }
    }

    // reduce + finalize
    aA0 += __shfl_xor(aA0, 16); aA0 += __shfl_xor(aA0, 32);
    aA1 += __shfl_xor(aA1, 16); aA1 += __shfl_xor(aA1, 32);
    aA2 += __shfl_xor(aA2, 16); aA2 += __shfl_xor(aA2, 32);
    aA3 += __shfl_xor(aA3, 16); aA3 += __shfl_xor(aA3, 32);
    aB0 += __shfl_xor(aB0, 16); aB0 += __shfl_xor(aB0, 32);
    aB1 += __shfl_xor(aB1, 16); aB1 += __shfl_xor(aB1, 32);
    aB2 += __shfl_xor(aB2, 16); aB2 += __shfl_xor(aB2, 32);
    aB3 += __shfl_xor(aB3, 16); aB3 += __shfl_xor(aB3, 32);
    if (validA && q == 0) {
        float4 hv;
        hv.x = fmaxf((aA0 + bflo(svA.x)) * diA + bq.x, 0.0f);
        hv.y = fmaxf((aA1 + bfhi(svA.x)) * diA + bq.y, 0.0f);
        hv.z = fmaxf((aA2 + bflo(svA.y)) * diA + bq.z, 0.0f);
        hv.w = fmaxf((aA3 + bfhi(svA.y)) * diA + bq.w, 0.0f);
        *(float4*)&hb[wid * 2][4 * j] = hv;
    }
    if (validB && q == 0) {
        float4 hv;
        hv.x = fmaxf((aB0 + bflo(svB.x)) * diB + bq.x, 0.0f);
        hv.y = fmaxf((aB1 + bfhi(svB.x)) * diB + bq.y, 0.0f);
        hv.z = fmaxf((aB2 + bflo(svB.y)) * diB + bq.z, 0.0f);
        hv.w = fmaxf((aB3 + bfhi(svB.y)) * diB + bq.w, 0.0f);
        *(float4*)&hb[wid * 2 + 1][4 * j] = hv;
    }
    __syncthreads();  // covers W2s staging and hb writes
    // GEMM2 split-k: half h sums k = h*32..h*32+31 for output col c
    int c = lane & 31, half = lane >> 5;
    int k0 = half * 32;
    if (validA) {
        float s = 0.0f;
        const float4* hb4 = (const float4*)&hb[wid * 2][k0];
#pragma unroll
        for (int kk = 0; kk < 8; kk++) {
            float4 h4 = hb4[kk];              // ds_read_b128, wave-uniform addr
            int kb = k0 + kk * 4;
            s = fmaf(h4.x, W2s[(kb + 0) * 32 + c], s);
            s = fmaf(h4.y, W2s[(kb + 1) * 32 + c], s);
            s = fmaf(h4.z, W2s[(kb + 2) * 32 + c], s);
            s = fmaf(h4.w, W2s[(kb + 3) * 32 + c], s);
        }
        s += __shfl_xor(s, 32);
        if (half == 0) h2b[(size_t)nodeA * 32 + c] = (unsigned short)bf16rn(s * diA);
    }
    if (validB) {
        float s = 0.0f;
        const float4* hb4 = (const float4*)&hb[wid * 2 + 1][k0];
#pragma unroll
        for (int kk = 0; kk < 8; kk++) {
            float4 h4 = hb4[kk];
            int kb = k0 + kk * 4;
            s = fmaf(h4.x, W2s[(kb + 0) * 32 + c], s);
            s = fmaf(h4.y, W2s[(kb + 1) * 32 + c], s);
            s = fmaf(h4.z, W2s[(kb + 2) * 32 + c], s);
            s = fmaf(h4.w, W2s[(kb + 3) * 32 + c], s);
        }
        s += __shfl_xor(s, 32);
        if (half == 0) h2b[(size_t)nodeB * 32 + c] = (unsigned short)bf16rn(s * diB);
    }
}

// ------- L2 gather + finalize — two nodes/wave + packed meta (optimum) ---------
// EIGHTH-wave (8 lanes x uint2 = 64B) reads one row; lane j holds cols 4j..4j+3.
__global__ __launch_bounds__(256) void k_gather_l2(const int4* __restrict__ meta,
                                                   const int* __restrict__ srclist,
                                                   const uint32* __restrict__ h2b,
                                                   const float* __restrict__ b2v,
                                                   float* __restrict__ out, int n) {
    int t = threadIdx.x;
    int wid = t >> 6, lane = t & 63;
    int nodeA = blockIdx.x * 8 + wid * 2;
    if (nodeA >= n) return;  // whole wave exits together (B too)
    int nodeB = nodeA + 1;
    bool validB = (nodeB < n);
    int j = lane & 7, o = lane >> 3;
    float4 bq = ((const float4*)b2v)[j];  // hoisted

    int4 mvA = meta[nodeA];
    int rowA = mvA.x, mA = mvA.y;
    float diA = __int_as_float(mvA.z);
    int rowB = 0, mB = 0;
    float diB = 0.0f;
    const uint2* h2v = (const uint2*)h2b;
    uint2 svA = h2v[(size_t)nodeA * 8 + j];
    uint2 svB = make_uint2(0u, 0u);
    if (validB) {
        int4 mvB = meta[nodeB];
        rowB = mvB.x; mB = mvB.y; diB = __int_as_float(mvB.z);
        svB = h2v[(size_t)nodeB * 8 + j];
    }
    int mA0 = min(64, mA), mB0 = min(64, mB);
    int sidxA = (lane < mA0) ? srclist[rowA + lane] : 0;
    int sidxB = (lane < mB0) ? srclist[rowB + lane] : 0;

    float aA0 = 0.f, aA1 = 0.f, aA2 = 0.f, aA3 = 0.f;
    float aB0 = 0.f, aB1 = 0.f, aB2 = 0.f, aB3 = 0.f;
    int jjA = 0, jjB = 0;
    // merged-16: 16 rows each, 4 row loads in flight
    for (; jjA + 16 <= mA0 && jjB + 16 <= mB0; jjA += 16, jjB += 16) {
        int sA0 = __shfl(sidxA, jjA + o), sA1 = __shfl(sidxA, jjA + 8 + o);
        int sB0 = __shfl(sidxB, jjB + o), sB1 = __shfl(sidxB, jjB + 8 + o);
        uint2 vA0 = h2v[(size_t)sA0 * 8 + j], vA1 = h2v[(size_t)sA1 * 8 + j];
        uint2 vB0 = h2v[(size_t)sB0 * 8 + j], vB1 = h2v[(size_t)sB1 * 8 + j];
        aA0 += bflo(vA0.x) + bflo(vA1.x);
        aA1 += bfhi(vA0.x) + bfhi(vA1.x);
        aA2 += bflo(vA0.y) + bflo(vA1.y);
        aA3 += bfhi(vA0.y) + bfhi(vA1.y);
        aB0 += bflo(vB0.x) + bflo(vB1.x);
        aB1 += bfhi(vB0.x) + bfhi(vB1.x);
        aB2 += bflo(vB0.y) + bflo(vB1.y);
        aB3 += bfhi(vB0.y) + bfhi(vB1.y);
    }
    // merged-8: 8 rows each, 2 row loads in flight
    for (; jjA + 8 <= mA0 && jjB + 8 <= mB0; jjA += 8, jjB += 8) {
        int sA0 = __shfl(sidxA, jjA + o);
        int sB0 = __shfl(sidxB, jjB + o);
        uint2 vA0 = h2v[(size_t)sA0 * 8 + j];
        uint2 vB0 = h2v[(size_t)sB0 * 8 + j];
        aA0 += bflo(vA0.x); aA1 += bfhi(vA0.x);
        aA2 += bflo(vA0.y); aA3 += bfhi(vA0.y);
        aB0 += bflo(vB0.x); aB1 += bfhi(vB0.x);
        aB2 += bflo(vB0.y); aB3 += bfhi(vB0.y);
    }
    // drain A
    for (; jjA + 8 <= mA0; jjA += 8) {
        int s0 = __shfl(sidxA, jjA + o);
        uint2 v0 = h2v[(size_t)s0 * 8 + j];
        aA0 += bflo(v0.x); aA1 += bfhi(v0.x);
        aA2 += bflo(v0.y); aA3 += bfhi(v0.y);
    }
    if (jjA < mA0) {
        int jidx = jjA + o;
        int s = __shfl(sidxA, min(jidx, mA0 - 1));
        uint2 v = h2v[(size_t)s * 8 + j];
        if (jidx < mA0) {
            aA0 += bflo(v.x); aA1 += bfhi(v.x);
            aA2 += bflo(v.y); aA3 += bfhi(v.y);
        }
    }
    // drain B
    for (; jjB + 8 <= mB0; jjB += 8) {
        int s0 = __shfl(sidxB, jjB + o);
        uint2 v0 = h2v[(size_t)s0 * 8 + j];
        aB0 += bflo(v0.x); aB1 += bfhi(v0.x);
        aB2 += bflo(v0.y); aB3 += bfhi(v0.y);
    }
    if (jjB < mB0) {
        int jidx = jjB + o;
        int s = __shfl(sidxB, min(jidx, mB0 - 1));
        uint2 v = h2v[(size_t)s * 8 + j];
        if (jidx < mB0) {
            aB0 += bflo(v.x); aB1 += bfhi(v.x);
            aB2 += bflo(v.y); aB3 += bfhi(v.y);
        }
    }
    // extra batches (degree > 64; kept for safety)
    for (int j0 = 64; j0 < mA; j0 += 64) {
        int m = min(64, mA - j0);
        int sb = (lane < m) ? srclist[rowA + j0 + lane] : 0;
        int jj = 0;
        for (; jj + 8 <= m; jj += 8) {
            int s0 = __shfl(sb, jj + o);
            uint2 v0 = h2v[(size_t)s0 * 8 + j];
            aA0 += bflo(v0.x); aA1 += bfhi(v0.x);
            aA2 += bflo(v0.y); aA3 += bfhi(v0.y);
        }
        if (jj < m) {
            int jidx = jj + o;
            int s = __shfl(sb, min(jidx, m - 1));
            uint2 v = h2v[(size_t)s * 8 + j];
            if (jidx < m) {
                aA0 += bflo(v.x); aA1 += bfhi(v.x);
                aA2 += bflo(v.y); aA3 += bfhi(v.y);
            }
        }
    }
    for (int j0 = 64; j0 < mB; j0 += 64) {
        int m = min(64, mB - j0);
        int sb = (lane < m) ? srclist[rowB + j0 + lane] : 0;
        int jj = 0;
        for (; jj + 8 <= m; jj += 8) {
            int s0 = __shfl(sb, jj + o);
            uint2 v0 = h2v[(size_t)s0 * 8 + j];
            aB0 += bflo(v0.x); aB1 += bfhi(v0.x);
            aB2 += bflo(v0.y); aB3 += bfhi(v0.y);
        }
        if (jj < m) {
            int jidx = jj + o;
            int s = __shfl(sb, min(jidx, m - 1));
            uint2 v = h2v[(size_t)s * 8 + j];
            if (jidx < m) {
                aB0 += bflo(v.x); aB1 += bfhi(v.x);
                aB2 += bflo(v.y); aB3 += bfhi(v.y);
            }
        }
    }

    aA0 += __shfl_xor(aA0, 8); aA0 += __shfl_xor(aA0, 16); aA0 += __shfl_xor(aA0, 32);
    aA1 += __shfl_xor(aA1, 8); aA1 += __shfl_xor(aA1, 16); aA1 += __shfl_xor(aA1, 32);
    aA2 += __shfl_xor(aA2, 8); aA2 += __shfl_xor(aA2, 16); aA2 += __shfl_xor(aA2, 32);
    aA3 += __shfl_xor(aA3, 8); aA3 += __shfl_xor(aA3, 16); aA3 += __shfl_xor(aA3, 32);
    aB0 += __shfl_xor(aB0, 8); aB0 += __shfl_xor(aB0, 16); aB0 += __shfl_xor(aB0, 32);
    aB1 += __shfl_xor(aB1, 8); aB1 += __shfl_xor(aB1, 16); aB1 += __shfl_xor(aB1, 32);
    aB2 += __shfl_xor(aB2, 8); aB2 += __shfl_xor(aB2, 16); aB2 += __shfl_xor(aB2, 32);
    aB3 += __shfl_xor(aB3, 8); aB3 += __shfl_xor(aB3, 16); aB3 += __shfl_xor(aB3, 32);
    if (o == 0) {
        float4 ov;
        ov.x = (aA0 + bflo(svA.x)) * diA + bq.x;
        ov.y = (aA1 + bfhi(svA.x)) * diA + bq.y;
        ov.z = (aA2 + bflo(svA.y)) * diA + bq.z;
        ov.w = (aA3 + bfhi(svA.y)) * diA + bq.w;
        ((float4*)out)[(size_t)nodeA * 8 + j] = ov;
        if (validB) {
            float4 ob;
            ob.x = (aB0 + bflo(svB.x)) * diB + bq.x;
            ob.y = (aB1 + bfhi(svB.x)) * diB + bq.y;
            ob.z = (aB2 + bflo(svB.y)) * diB + bq.z;
            ob.w = (aB3 + bfhi(svB.y)) * diB + bq.w;
            ((float4*)out)[(size_t)nodeB * 8 + j] = ob;
        }
    }
}

extern "C" void kernel_launch(void* const* d_in, const int* in_sizes, int n_in,
                              void* d_out, int out_size, void* d_ws, size_t ws_size,
                              hipStream_t stream) {
    const float* x  = (const float*)d_in[0];
    const int*   ei = (const int*)d_in[1];
    const float* W1 = (const float*)d_in[2];
    const float* b1 = (const float*)d_in[3];
    const float* W2 = (const float*)d_in[4];
    const float* b2 = (const float*)d_in[5];
    float* out = (float*)d_out;

    const int N = in_sizes[0] / 128;  // 100000
    const int E = in_sizes[1] / 2;    // 1600000
    const int* src = ei;
    const int* dst = ei + E;
    const int nbuck = (N + 255) >> 8;  // 391

    // per-bucket capacity: mean + mean/8 + 256, rounded up to 64 (~mu+10sigma)
    int mean = (E + nbuck - 1) / nbuck;
    int cap = (mean + (mean >> 3) + 256 + 63) & ~63;     // 4864 for this input
    size_t region = (size_t)nbuck * cap;                 // ~1.9M entries, 7.6 MB

    char* p = (char*)d_ws;
    uint32* pairs      = (uint32*)p;    p += region * 4;          // 7.6 MB
    int* srclist       = (int*)p;       p += region * 4;          // 7.6 MB
    uint32* h1b        = (uint32*)p;    p += (size_t)N * 64 * 2;  // 12.8 MB
    uint32* h2b        = (uint32*)p;    p += (size_t)N * 32 * 2;  // 6.4 MB
    int* cursor        = (int*)p;       p += MAXBUCK * CURSTRIDE * 4;  // 32 KB
    int4* meta         = (int4*)p;      p += (size_t)N * 16;      // 1.6 MB packed meta
    float* dinv        = (float*)p;     p += (size_t)N * 4;       // total ~38 MB

    // zero-based per-bucket cursors (init via memset, no initcur launch)
    hipMemsetAsync(cursor, 0, (size_t)nbuck * CURSTRIDE * 4, stream);
    k_bin<<<(E + 4095) / 4096, 1024, 0, stream>>>(src, dst, E, nbuck, cap, cursor, pairs);
    k_fill2<<<nbuck, 1024, 0, stream>>>(pairs, cursor, cap, N, srclist, meta, dinv);

    k_gemm1<<<(N + 31) / 32, 256, 0, stream>>>(x, W1, dinv, h1b, N);
    k_gather_l1<<<(N + 7) / 8, 256, 0, stream>>>(meta, srclist, h1b,
                                                 b1, W2, (unsigned short*)h2b, N);
    k_gather_l2<<<(N + 7) / 8, 256, 0, stream>>>(meta, srclist, h2b, b2, out, N);
}